// Round 1
// baseline (1010.702 us; speedup 1.0000x reference)
//
#include <hip/hip_runtime.h>

#define NN 100000      // nodes
#define DD 128         // embedding dim
#define KE 300         // raw feature dim
#define NE 1600000     // edges
#define NB 4096        // batch (users)
#define HL 50          // history length
#define CL 20          // candidates

// ---------------- encoder GEMM: out[M,128] = x[M,300] @ W[300,128] (fp32) ---
// block 256 = 16 row-threads x 16 col-threads; per thread 4 rows x 8 cols.
__global__ __launch_bounds__(256) void enc_gemm(const float* __restrict__ x,
                                                const float* __restrict__ W,
                                                float* __restrict__ out) {
    __shared__ float At[20][64];    // A tile transposed [k][r]
    __shared__ float Bs[20][128];   // B tile [k][c]
    const int tid = threadIdx.x;
    const int rt = tid >> 4;        // 0..15
    const int ct = tid & 15;        // 0..15
    const int row0 = blockIdx.x * 64;

    float acc[4][8];
#pragma unroll
    for (int i = 0; i < 4; ++i)
#pragma unroll
        for (int j = 0; j < 8; ++j) acc[i][j] = 0.f;

    for (int k0 = 0; k0 < KE; k0 += 20) {
        // A tile: 64 rows x 20 k  (1280 elems, 5 per thread), store transposed
#pragma unroll
        for (int l = 0; l < 5; ++l) {
            int i = tid + l * 256;
            int r = i / 20, k = i - r * 20;
            int row = row0 + r;
            At[k][r] = (row < NN) ? x[row * KE + k0 + k] : 0.f;
        }
        // B tile: 20 k x 128 c (2560 elems, 10 per thread), coalesced
#pragma unroll
        for (int l = 0; l < 10; ++l) {
            int i = tid + l * 256;
            int k = i >> 7, c = i & 127;
            Bs[k][c] = W[(k0 + k) * DD + c];
        }
        __syncthreads();
#pragma unroll
        for (int k = 0; k < 20; ++k) {
            const float4 a  = *(const float4*)&At[k][rt * 4];
            const float4 b0 = *(const float4*)&Bs[k][ct * 8];
            const float4 b1 = *(const float4*)&Bs[k][ct * 8 + 4];
            float av[4] = {a.x, a.y, a.z, a.w};
            float bv[8] = {b0.x, b0.y, b0.z, b0.w, b1.x, b1.y, b1.z, b1.w};
#pragma unroll
            for (int i = 0; i < 4; ++i)
#pragma unroll
                for (int j = 0; j < 8; ++j)
                    acc[i][j] = fmaf(av[i], bv[j], acc[i][j]);
        }
        __syncthreads();
    }
#pragma unroll
    for (int i = 0; i < 4; ++i) {
        int row = row0 + rt * 4 + i;
        if (row < NN) {
            float4 o0 = make_float4(acc[i][0], acc[i][1], acc[i][2], acc[i][3]);
            float4 o1 = make_float4(acc[i][4], acc[i][5], acc[i][6], acc[i][7]);
            *(float4*)&out[row * DD + ct * 8]     = o0;
            *(float4*)&out[row * DD + ct * 8 + 4] = o1;
        }
    }
}

// ---------------- edge aggregation: agg[dst] += news[src], deg[dst] += 1 ----
// 128 threads per edge (one per embedding element), 2 edges per 256-block.
__global__ __launch_bounds__(256) void edge_agg(const int* __restrict__ ei,
                                                const float* __restrict__ news,
                                                float* __restrict__ agg,
                                                float* __restrict__ deg) {
    long long g = (long long)blockIdx.x * 256 + threadIdx.x;
    int e = (int)(g >> 7);
    int t = (int)(g & 127);
    if (e >= NE) return;
    int src = ei[e];
    int dst = ei[NE + e];
    float v = news[(long long)src * DD + t];
    atomicAdd(&agg[(long long)dst * DD + t], v);
    if (t == 0) atomicAdd(&deg[dst], 1.0f);
}

// ---------------- gnn GEMM + epilogue: xx = news + (agg @ W) * inv_deg ------
__global__ __launch_bounds__(256) void gnn_gemm(const float* __restrict__ agg,
                                                const float* __restrict__ W,
                                                const float* __restrict__ deg,
                                                float* __restrict__ inout) {
    __shared__ float At[32][64];
    __shared__ float Bs[32][128];
    const int tid = threadIdx.x;
    const int rt = tid >> 4;
    const int ct = tid & 15;
    const int row0 = blockIdx.x * 64;

    float acc[4][8];
#pragma unroll
    for (int i = 0; i < 4; ++i)
#pragma unroll
        for (int j = 0; j < 8; ++j) acc[i][j] = 0.f;

    for (int k0 = 0; k0 < DD; k0 += 32) {
        // A tile: 64 rows x 32 k (2048 elems, 8/thread), coalesced 128B rows
#pragma unroll
        for (int l = 0; l < 8; ++l) {
            int i = tid + l * 256;
            int r = i >> 5, k = i & 31;
            int row = row0 + r;
            At[k][r] = (row < NN) ? agg[(long long)row * DD + k0 + k] : 0.f;
        }
        // B tile: 32 x 128 (4096 elems, 16/thread)
#pragma unroll
        for (int l = 0; l < 16; ++l) {
            int i = tid + l * 256;
            int k = i >> 7, c = i & 127;
            Bs[k][c] = W[(k0 + k) * DD + c];
        }
        __syncthreads();
#pragma unroll
        for (int k = 0; k < 32; ++k) {
            const float4 a  = *(const float4*)&At[k][rt * 4];
            const float4 b0 = *(const float4*)&Bs[k][ct * 8];
            const float4 b1 = *(const float4*)&Bs[k][ct * 8 + 4];
            float av[4] = {a.x, a.y, a.z, a.w};
            float bv[8] = {b0.x, b0.y, b0.z, b0.w, b1.x, b1.y, b1.z, b1.w};
#pragma unroll
            for (int i = 0; i < 4; ++i)
#pragma unroll
                for (int j = 0; j < 8; ++j)
                    acc[i][j] = fmaf(av[i], bv[j], acc[i][j]);
        }
        __syncthreads();
    }
#pragma unroll
    for (int i = 0; i < 4; ++i) {
        int row = row0 + rt * 4 + i;
        if (row < NN) {
            float s = 1.f / fmaxf(deg[row], 1.f);
            float4 n0 = *(const float4*)&inout[row * DD + ct * 8];
            float4 n1 = *(const float4*)&inout[row * DD + ct * 8 + 4];
            float4 o0 = make_float4(n0.x + acc[i][0] * s, n0.y + acc[i][1] * s,
                                    n0.z + acc[i][2] * s, n0.w + acc[i][3] * s);
            float4 o1 = make_float4(n1.x + acc[i][4] * s, n1.y + acc[i][5] * s,
                                    n1.z + acc[i][6] * s, n1.w + acc[i][7] * s);
            *(float4*)&inout[row * DD + ct * 8]     = o0;
            *(float4*)&inout[row * DD + ct * 8 + 4] = o1;
        }
    }
}

// ---------------- user vector: mean of masked history embeddings ------------
__global__ __launch_bounds__(128) void user_vec_k(const int* __restrict__ hist,
                                                  const float* __restrict__ xx,
                                                  float* __restrict__ uv) {
    int b = blockIdx.x, t = threadIdx.x;
    float s = 0.f, cnt = 0.f;
    for (int h = 0; h < HL; ++h) {
        int id = hist[b * HL + h];
        if (id != 0) { s += xx[(long long)id * DD + t]; cnt += 1.f; }
    }
    uv[b * DD + t] = s / fmaxf(cnt, 1e-9f);
}

// ---------------- scores: dot(cand_emb, user_vec) ---------------------------
__global__ __launch_bounds__(64) void scores_k(const int* __restrict__ cand,
                                               const float* __restrict__ xx,
                                               const float* __restrict__ uv,
                                               float* __restrict__ out) {
    int b = blockIdx.x, t = threadIdx.x;
    float u0 = uv[b * DD + t];
    float u1 = uv[b * DD + 64 + t];
    for (int c = 0; c < CL; ++c) {
        int id = cand[b * CL + c];
        float p = u0 * xx[(long long)id * DD + t] +
                  u1 * xx[(long long)id * DD + 64 + t];
#pragma unroll
        for (int off = 32; off >= 1; off >>= 1) p += __shfl_xor(p, off);
        if (t == 0) out[b * CL + c] = p;
    }
}

extern "C" void kernel_launch(void* const* d_in, const int* in_sizes, int n_in,
                              void* d_out, int out_size, void* d_ws, size_t ws_size,
                              hipStream_t stream) {
    const float* x    = (const float*)d_in[0];
    // d_in[1] = n_id == arange(N)  -> identity scatter, unused
    const int*   ei   = (const int*)d_in[2];
    const int*   hist = (const int*)d_in[3];
    const int*   cand = (const int*)d_in[4];
    const float* Wenc = (const float*)d_in[5];
    const float* Wgnn = (const float*)d_in[6];
    float* out = (float*)d_out;

    float* news = (float*)d_ws;            // [NN*DD] -> later holds xx in place
    float* agg  = news + (size_t)NN * DD;  // [NN*DD]
    float* deg  = agg  + (size_t)NN * DD;  // [NN]
    float* uv   = deg  + NN;               // [NB*DD]

    // zero agg + deg (contiguous region)
    hipMemsetAsync(agg, 0, ((size_t)NN * DD + NN) * sizeof(float), stream);

    int gemm_grid = (NN + 63) / 64;
    enc_gemm<<<gemm_grid, 256, 0, stream>>>(x, Wenc, news);
    edge_agg<<<(NE * 128 + 255) / 256, 256, 0, stream>>>(ei, news, agg, deg);
    gnn_gemm<<<gemm_grid, 256, 0, stream>>>(agg, Wgnn, deg, news);
    user_vec_k<<<NB, 128, 0, stream>>>(hist, news, uv);
    scores_k<<<NB, 64, 0, stream>>>(cand, news, uv, out);
}

// Round 2
// 591.951 us; speedup vs baseline: 1.7074x; 1.7074x over previous
//
#include <hip/hip_runtime.h>

#define NN 100000      // nodes
#define DD 128         // embedding dim
#define KE 300         // raw feature dim
#define NE 1600000     // edges
#define NB 4096        // batch (users)
#define HL 50          // history length
#define CL 20          // candidates
#define NBLK ((NN + 255) / 256)   // 391 scan blocks

// ---------------- encoder GEMM: out[M,128] = x[M,300] @ W[300,128] (fp32) ---
__global__ __launch_bounds__(256) void enc_gemm(const float* __restrict__ x,
                                                const float* __restrict__ W,
                                                float* __restrict__ out) {
    __shared__ float At[20][64];    // A tile transposed [k][r]
    __shared__ float Bs[20][128];   // B tile [k][c]
    const int tid = threadIdx.x;
    const int rt = tid >> 4;        // 0..15
    const int ct = tid & 15;        // 0..15
    const int row0 = blockIdx.x * 64;

    float acc[4][8];
#pragma unroll
    for (int i = 0; i < 4; ++i)
#pragma unroll
        for (int j = 0; j < 8; ++j) acc[i][j] = 0.f;

    for (int k0 = 0; k0 < KE; k0 += 20) {
#pragma unroll
        for (int l = 0; l < 5; ++l) {
            int i = tid + l * 256;
            int r = i / 20, k = i - r * 20;
            int row = row0 + r;
            At[k][r] = (row < NN) ? x[row * KE + k0 + k] : 0.f;
        }
#pragma unroll
        for (int l = 0; l < 10; ++l) {
            int i = tid + l * 256;
            int k = i >> 7, c = i & 127;
            Bs[k][c] = W[(k0 + k) * DD + c];
        }
        __syncthreads();
#pragma unroll
        for (int k = 0; k < 20; ++k) {
            const float4 a  = *(const float4*)&At[k][rt * 4];
            const float4 b0 = *(const float4*)&Bs[k][ct * 8];
            const float4 b1 = *(const float4*)&Bs[k][ct * 8 + 4];
            float av[4] = {a.x, a.y, a.z, a.w};
            float bv[8] = {b0.x, b0.y, b0.z, b0.w, b1.x, b1.y, b1.z, b1.w};
#pragma unroll
            for (int i = 0; i < 4; ++i)
#pragma unroll
                for (int j = 0; j < 8; ++j)
                    acc[i][j] = fmaf(av[i], bv[j], acc[i][j]);
        }
        __syncthreads();
    }
#pragma unroll
    for (int i = 0; i < 4; ++i) {
        int row = row0 + rt * 4 + i;
        if (row < NN) {
            float4 o0 = make_float4(acc[i][0], acc[i][1], acc[i][2], acc[i][3]);
            float4 o1 = make_float4(acc[i][4], acc[i][5], acc[i][6], acc[i][7]);
            *(float4*)&out[row * DD + ct * 8]     = o0;
            *(float4*)&out[row * DD + ct * 8 + 4] = o1;
        }
    }
}

// ---------------- CSR build step 1: degree histogram ------------------------
__global__ __launch_bounds__(256) void k_hist(const int* __restrict__ ei,
                                              int* __restrict__ deg) {
    int e = blockIdx.x * 256 + threadIdx.x;
    if (e < NE) atomicAdd(&deg[ei[NE + e]], 1);
}

// ---------------- CSR step 2a: per-block exclusive scan of deg --------------
__global__ __launch_bounds__(256) void k_scan1(const int* __restrict__ deg,
                                               int* __restrict__ rs,
                                               int* __restrict__ bsum) {
    __shared__ int s[256];
    int t = threadIdx.x, idx = blockIdx.x * 256 + t;
    int v = (idx < NN) ? deg[idx] : 0;
    s[t] = v;
    __syncthreads();
#pragma unroll
    for (int off = 1; off < 256; off <<= 1) {
        int add = (t >= off) ? s[t - off] : 0;
        __syncthreads();
        s[t] += add;
        __syncthreads();
    }
    if (idx < NN) rs[idx] = s[t] - v;          // exclusive within block
    if (t == 255) bsum[blockIdx.x] = s[255];   // block total
}

// ---------------- CSR step 2b: scan block sums (NBLK=391 <= 512) ------------
__global__ __launch_bounds__(512) void k_scan2(const int* __restrict__ bsum,
                                               int* __restrict__ boff) {
    __shared__ int s[512];
    int t = threadIdx.x;
    int v = (t < NBLK) ? bsum[t] : 0;
    s[t] = v;
    __syncthreads();
#pragma unroll
    for (int off = 1; off < 512; off <<= 1) {
        int add = (t >= off) ? s[t - off] : 0;
        __syncthreads();
        s[t] += add;
        __syncthreads();
    }
    if (t < NBLK) boff[t] = s[t] - v;          // exclusive block offsets
}

// ---------------- CSR step 3: scatter src ids into dst-grouped order --------
__global__ __launch_bounds__(256) void k_scatter(const int* __restrict__ ei,
                                                 const int* __restrict__ rs,
                                                 const int* __restrict__ boff,
                                                 int* __restrict__ cursor,
                                                 int* __restrict__ ssrc) {
    int e = blockIdx.x * 256 + threadIdx.x;
    if (e >= NE) return;
    int src = ei[e];
    int dst = ei[NE + e];
    int pos = rs[dst] + boff[dst >> 8] + atomicAdd(&cursor[dst], 1);
    ssrc[pos] = src;
}

// ---------------- aggregation: one wave per dst node, no atomics ------------
__global__ __launch_bounds__(256) void k_aggregate(const int* __restrict__ ssrc,
                                                   const int* __restrict__ rs,
                                                   const int* __restrict__ boff,
                                                   const int* __restrict__ deg,
                                                   const float* __restrict__ news,
                                                   float* __restrict__ agg) {
    int n = blockIdx.x * 4 + (threadIdx.x >> 6);   // node id (wave per node)
    int lane = threadIdx.x & 63;
    if (n >= NN) return;
    int start = rs[n] + boff[n >> 8];
    int cnt = deg[n];
    float2 acc = make_float2(0.f, 0.f);
    for (int i = 0; i < cnt; ++i) {
        int src = ssrc[start + i];
        float2 v = *(const float2*)&news[(long long)src * DD + lane * 2];
        acc.x += v.x;
        acc.y += v.y;
    }
    *(float2*)&agg[(long long)n * DD + lane * 2] = acc;
}

// ---------------- gnn GEMM + epilogue: xx = news + (agg @ W) * inv_deg ------
__global__ __launch_bounds__(256) void gnn_gemm(const float* __restrict__ agg,
                                                const float* __restrict__ W,
                                                const int* __restrict__ deg,
                                                float* __restrict__ inout) {
    __shared__ float At[32][64];
    __shared__ float Bs[32][128];
    const int tid = threadIdx.x;
    const int rt = tid >> 4;
    const int ct = tid & 15;
    const int row0 = blockIdx.x * 64;

    float acc[4][8];
#pragma unroll
    for (int i = 0; i < 4; ++i)
#pragma unroll
        for (int j = 0; j < 8; ++j) acc[i][j] = 0.f;

    for (int k0 = 0; k0 < DD; k0 += 32) {
#pragma unroll
        for (int l = 0; l < 8; ++l) {
            int i = tid + l * 256;
            int r = i >> 5, k = i & 31;
            int row = row0 + r;
            At[k][r] = (row < NN) ? agg[(long long)row * DD + k0 + k] : 0.f;
        }
#pragma unroll
        for (int l = 0; l < 16; ++l) {
            int i = tid + l * 256;
            int k = i >> 7, c = i & 127;
            Bs[k][c] = W[(k0 + k) * DD + c];
        }
        __syncthreads();
#pragma unroll
        for (int k = 0; k < 32; ++k) {
            const float4 a  = *(const float4*)&At[k][rt * 4];
            const float4 b0 = *(const float4*)&Bs[k][ct * 8];
            const float4 b1 = *(const float4*)&Bs[k][ct * 8 + 4];
            float av[4] = {a.x, a.y, a.z, a.w};
            float bv[8] = {b0.x, b0.y, b0.z, b0.w, b1.x, b1.y, b1.z, b1.w};
#pragma unroll
            for (int i = 0; i < 4; ++i)
#pragma unroll
                for (int j = 0; j < 8; ++j)
                    acc[i][j] = fmaf(av[i], bv[j], acc[i][j]);
        }
        __syncthreads();
    }
#pragma unroll
    for (int i = 0; i < 4; ++i) {
        int row = row0 + rt * 4 + i;
        if (row < NN) {
            float s = 1.f / fmaxf((float)deg[row], 1.f);
            float4 n0 = *(const float4*)&inout[row * DD + ct * 8];
            float4 n1 = *(const float4*)&inout[row * DD + ct * 8 + 4];
            float4 o0 = make_float4(n0.x + acc[i][0] * s, n0.y + acc[i][1] * s,
                                    n0.z + acc[i][2] * s, n0.w + acc[i][3] * s);
            float4 o1 = make_float4(n1.x + acc[i][4] * s, n1.y + acc[i][5] * s,
                                    n1.z + acc[i][6] * s, n1.w + acc[i][7] * s);
            *(float4*)&inout[row * DD + ct * 8]     = o0;
            *(float4*)&inout[row * DD + ct * 8 + 4] = o1;
        }
    }
}

// ---------------- user vector: mean of masked history embeddings ------------
__global__ __launch_bounds__(128) void user_vec_k(const int* __restrict__ hist,
                                                  const float* __restrict__ xx,
                                                  float* __restrict__ uv) {
    int b = blockIdx.x, t = threadIdx.x;
    float s = 0.f, cnt = 0.f;
    for (int h = 0; h < HL; ++h) {
        int id = hist[b * HL + h];
        if (id != 0) { s += xx[(long long)id * DD + t]; cnt += 1.f; }
    }
    uv[b * DD + t] = s / fmaxf(cnt, 1e-9f);
}

// ---------------- scores: dot(cand_emb, user_vec) ---------------------------
__global__ __launch_bounds__(64) void scores_k(const int* __restrict__ cand,
                                               const float* __restrict__ xx,
                                               const float* __restrict__ uv,
                                               float* __restrict__ out) {
    int b = blockIdx.x, t = threadIdx.x;
    float u0 = uv[b * DD + t];
    float u1 = uv[b * DD + 64 + t];
    for (int c = 0; c < CL; ++c) {
        int id = cand[b * CL + c];
        float p = u0 * xx[(long long)id * DD + t] +
                  u1 * xx[(long long)id * DD + 64 + t];
#pragma unroll
        for (int off = 32; off >= 1; off >>= 1) p += __shfl_xor(p, off);
        if (t == 0) out[b * CL + c] = p;
    }
}

extern "C" void kernel_launch(void* const* d_in, const int* in_sizes, int n_in,
                              void* d_out, int out_size, void* d_ws, size_t ws_size,
                              hipStream_t stream) {
    const float* x    = (const float*)d_in[0];
    // d_in[1] = n_id == arange(N) -> identity scatter, unused
    const int*   ei   = (const int*)d_in[2];
    const int*   hist = (const int*)d_in[3];
    const int*   cand = (const int*)d_in[4];
    const float* Wenc = (const float*)d_in[5];
    const float* Wgnn = (const float*)d_in[6];
    float* out = (float*)d_out;

    float* news  = (float*)d_ws;               // [NN*DD], later holds xx
    float* agg   = news + (size_t)NN * DD;     // [NN*DD]
    float* uv    = agg  + (size_t)NN * DD;     // [NB*DD]
    int*   deg   = (int*)(uv + (size_t)NB * DD); // [NN]
    int*   cur   = deg + NN;                   // [NN]
    int*   rs    = cur + NN;                   // [NN]
    int*   bsum  = rs + NN;                    // [NBLK]
    int*   boff  = bsum + NBLK;                // [NBLK]
    int*   ssrc  = boff + NBLK;                // [NE]

    // zero deg + cursor (contiguous)
    hipMemsetAsync(deg, 0, 2 * (size_t)NN * sizeof(int), stream);

    int gemm_grid = (NN + 63) / 64;
    enc_gemm<<<gemm_grid, 256, 0, stream>>>(x, Wenc, news);

    k_hist<<<(NE + 255) / 256, 256, 0, stream>>>(ei, deg);
    k_scan1<<<NBLK, 256, 0, stream>>>(deg, rs, bsum);
    k_scan2<<<1, 512, 0, stream>>>(bsum, boff);
    k_scatter<<<(NE + 255) / 256, 256, 0, stream>>>(ei, rs, boff, cur, ssrc);
    k_aggregate<<<(NN + 3) / 4, 256, 0, stream>>>(ssrc, rs, boff, deg, news, agg);

    gnn_gemm<<<gemm_grid, 256, 0, stream>>>(agg, Wgnn, deg, news);
    user_vec_k<<<NB, 128, 0, stream>>>(hist, news, uv);
    scores_k<<<NB, 64, 0, stream>>>(cand, news, uv, out);
}

// Round 3
// 422.764 us; speedup vs baseline: 2.3907x; 1.4002x over previous
//
#include <hip/hip_runtime.h>

#define NN 100000      // nodes
#define DD 128         // embedding dim
#define KE 300         // raw feature dim
#define KP 320         // padded K for enc
#define NE 1600000     // edges
#define NB 4096        // batch (users)
#define HL 50          // history length
#define CL 20          // candidates
#define NBLK ((NN + 255) / 256)   // 391 scan blocks

typedef unsigned short ushort_t;
using bf16x8 = __attribute__((ext_vector_type(8))) short;
using f32x4  = __attribute__((ext_vector_type(4))) float;

__device__ __forceinline__ ushort_t f2bf(float f) {
    unsigned u = __float_as_uint(f);
    unsigned r = u + 0x7FFF + ((u >> 16) & 1);   // RNE
    return (ushort_t)(r >> 16);
}
__device__ __forceinline__ float bf2f(unsigned s) {
    return __uint_as_float(s << 16);
}

// ---------------- weight prep: transpose + convert to bf16 ------------------
// wt_enc[n][k] (128 x 320, zero-padded k>=300), wt_gnn[n][k] (128 x 128)
__global__ __launch_bounds__(256) void prep_w(const float* __restrict__ We,
                                              const float* __restrict__ Wg,
                                              ushort_t* __restrict__ wte,
                                              ushort_t* __restrict__ wtg) {
    int i = blockIdx.x * 256 + threadIdx.x;
    if (i < 128 * KP) {
        int n = i / KP, k = i - n * KP;
        float v = (k < KE) ? We[k * DD + n] : 0.f;
        wte[n * KP + k] = f2bf(v);
    } else if (i < 128 * KP + 128 * 128) {
        int j = i - 128 * KP;
        int n = j >> 7, k = j & 127;
        wtg[n * DD + k] = f2bf(Wg[k * DD + n]);
    }
}

// ---------------- encoder: news_bf[M,128] = bf16( x[M,300] @ W[300,128] ) ---
// 128x128 tile, 4 waves, MFMA 16x16x32 bf16. LDS stride 40 kills conflicts.
__global__ __launch_bounds__(256) void enc_mfma(const float* __restrict__ x,
                                                const ushort_t* __restrict__ wt,
                                                ushort_t* __restrict__ news) {
    __shared__ ushort_t As[128][40];   // [row][k] bf16
    __shared__ ushort_t Bs[128][40];   // [col][k] bf16 (B^T)
    const int tid = threadIdx.x;
    const int w = tid >> 6, lane = tid & 63;
    const int hl = lane & 15, kg = lane >> 4;
    const int row0 = blockIdx.x * 128;
    const int sr = tid >> 1, sh = tid & 1;      // staging: row, half

    f32x4 acc[2][8];
#pragma unroll
    for (int i = 0; i < 2; ++i)
#pragma unroll
        for (int j = 0; j < 8; ++j) acc[i][j] = (f32x4)0.f;

    for (int k0 = 0; k0 < KP; k0 += 32) {
        // ---- stage A: 128 rows x 32 k, fp32 -> bf16, 16 floats/thread
        {
            int row = row0 + sr;
            int kb = k0 + sh * 16;
            float v[16];
            if (row < NN && kb + 16 <= KE) {
                const float4* px = (const float4*)&x[(long long)row * KE + kb];
                float4 a0 = px[0], a1 = px[1], a2 = px[2], a3 = px[3];
                v[0]=a0.x; v[1]=a0.y; v[2]=a0.z; v[3]=a0.w;
                v[4]=a1.x; v[5]=a1.y; v[6]=a1.z; v[7]=a1.w;
                v[8]=a2.x; v[9]=a2.y; v[10]=a2.z; v[11]=a2.w;
                v[12]=a3.x; v[13]=a3.y; v[14]=a3.z; v[15]=a3.w;
            } else {
#pragma unroll
                for (int j = 0; j < 16; ++j) {
                    int k = kb + j;
                    v[j] = (row < NN && k < KE) ? x[(long long)row * KE + k] : 0.f;
                }
            }
            unsigned p[8];
#pragma unroll
            for (int j = 0; j < 8; ++j)
                p[j] = (unsigned)f2bf(v[2*j]) | ((unsigned)f2bf(v[2*j+1]) << 16);
            uint4* dst = (uint4*)&As[sr][sh * 16];
            dst[0] = make_uint4(p[0], p[1], p[2], p[3]);
            dst[1] = make_uint4(p[4], p[5], p[6], p[7]);
        }
        // ---- stage B: 128 cols x 32 k bf16, 16 ushorts/thread
        {
            const uint4* src = (const uint4*)&wt[sr * KP + k0 + sh * 16];
            uint4* dst = (uint4*)&Bs[sr][sh * 16];
            dst[0] = src[0];
            dst[1] = src[1];
        }
        __syncthreads();
        // ---- MFMA: wave w owns rows [w*32, w*32+32)
        bf16x8 af[2], bf[8];
#pragma unroll
        for (int rf = 0; rf < 2; ++rf)
            af[rf] = *(const bf16x8*)&As[w * 32 + rf * 16 + hl][kg * 8];
#pragma unroll
        for (int cf = 0; cf < 8; ++cf)
            bf[cf] = *(const bf16x8*)&Bs[cf * 16 + hl][kg * 8];
#pragma unroll
        for (int rf = 0; rf < 2; ++rf)
#pragma unroll
            for (int cf = 0; cf < 8; ++cf)
                acc[rf][cf] = __builtin_amdgcn_mfma_f32_16x16x32_bf16(
                    af[rf], bf[cf], acc[rf][cf], 0, 0, 0);
        __syncthreads();
    }
    // ---- epilogue: C[row][col], col = lane&15, row = (lane>>4)*4 + reg
#pragma unroll
    for (int rf = 0; rf < 2; ++rf)
#pragma unroll
        for (int cf = 0; cf < 8; ++cf)
#pragma unroll
            for (int j = 0; j < 4; ++j) {
                int grow = row0 + w * 32 + rf * 16 + kg * 4 + j;
                int gcol = cf * 16 + hl;
                if (grow < NN)
                    news[(long long)grow * DD + gcol] = f2bf(acc[rf][cf][j]);
            }
}

// ---------------- CSR build step 1: degree histogram ------------------------
__global__ __launch_bounds__(256) void k_hist(const int* __restrict__ ei,
                                              int* __restrict__ deg) {
    int e = blockIdx.x * 256 + threadIdx.x;
    if (e < NE) atomicAdd(&deg[ei[NE + e]], 1);
}

// ---------------- CSR step 2a: per-block exclusive scan of deg --------------
__global__ __launch_bounds__(256) void k_scan1(const int* __restrict__ deg,
                                               int* __restrict__ rs,
                                               int* __restrict__ bsum) {
    __shared__ int s[256];
    int t = threadIdx.x, idx = blockIdx.x * 256 + t;
    int v = (idx < NN) ? deg[idx] : 0;
    s[t] = v;
    __syncthreads();
#pragma unroll
    for (int off = 1; off < 256; off <<= 1) {
        int add = (t >= off) ? s[t - off] : 0;
        __syncthreads();
        s[t] += add;
        __syncthreads();
    }
    if (idx < NN) rs[idx] = s[t] - v;
    if (t == 255) bsum[blockIdx.x] = s[255];
}

// ---------------- CSR step 2b: scan block sums ------------------------------
__global__ __launch_bounds__(512) void k_scan2(const int* __restrict__ bsum,
                                               int* __restrict__ boff) {
    __shared__ int s[512];
    int t = threadIdx.x;
    int v = (t < NBLK) ? bsum[t] : 0;
    s[t] = v;
    __syncthreads();
#pragma unroll
    for (int off = 1; off < 512; off <<= 1) {
        int add = (t >= off) ? s[t - off] : 0;
        __syncthreads();
        s[t] += add;
        __syncthreads();
    }
    if (t < NBLK) boff[t] = s[t] - v;
}

// ---------------- CSR step 3: scatter src ids into dst-grouped order --------
__global__ __launch_bounds__(256) void k_scatter(const int* __restrict__ ei,
                                                 const int* __restrict__ rs,
                                                 const int* __restrict__ boff,
                                                 int* __restrict__ cursor,
                                                 int* __restrict__ ssrc) {
    int e = blockIdx.x * 256 + threadIdx.x;
    if (e >= NE) return;
    int src = ei[e];
    int dst = ei[NE + e];
    int pos = rs[dst] + boff[dst >> 8] + atomicAdd(&cursor[dst], 1);
    ssrc[pos] = src;
}

// ---------------- aggregation: one wave per dst node, bf16 gather -----------
__global__ __launch_bounds__(256) void k_aggregate(const int* __restrict__ ssrc,
                                                   const int* __restrict__ rs,
                                                   const int* __restrict__ boff,
                                                   const int* __restrict__ deg,
                                                   const ushort_t* __restrict__ news,
                                                   ushort_t* __restrict__ agg) {
    int n = blockIdx.x * 4 + (threadIdx.x >> 6);
    int lane = threadIdx.x & 63;
    if (n >= NN) return;
    int start = rs[n] + boff[n >> 8];
    int cnt = deg[n];
    float a0 = 0.f, a1 = 0.f;
    for (int i = 0; i < cnt; ++i) {
        int src = ssrc[start + i];
        unsigned v = *(const unsigned*)&news[(long long)src * DD + lane * 2];
        a0 += bf2f(v & 0xFFFFu);
        a1 += bf2f(v >> 16);
    }
    unsigned o = (unsigned)f2bf(a0) | ((unsigned)f2bf(a1) << 16);
    *(unsigned*)&agg[(long long)n * DD + lane * 2] = o;
}

// ---------------- gnn: xx = f32(news) + (agg @ Wgnn) / deg  (MFMA bf16) -----
__global__ __launch_bounds__(256) void gnn_mfma(const ushort_t* __restrict__ aggb,
                                                const ushort_t* __restrict__ wt,
                                                const int* __restrict__ deg,
                                                const ushort_t* __restrict__ newsb,
                                                float* __restrict__ xx) {
    __shared__ ushort_t As[128][40];
    __shared__ ushort_t Bs[128][40];
    const int tid = threadIdx.x;
    const int w = tid >> 6, lane = tid & 63;
    const int hl = lane & 15, kg = lane >> 4;
    const int row0 = blockIdx.x * 128;
    const int sr = tid >> 1, sh = tid & 1;

    f32x4 acc[2][8];
#pragma unroll
    for (int i = 0; i < 2; ++i)
#pragma unroll
        for (int j = 0; j < 8; ++j) acc[i][j] = (f32x4)0.f;

    for (int k0 = 0; k0 < DD; k0 += 32) {
        {   // stage A (bf16 agg rows)
            int row = row0 + sr;
            uint4 a0, a1;
            if (row < NN) {
                const uint4* src = (const uint4*)&aggb[(long long)row * DD + k0 + sh * 16];
                a0 = src[0]; a1 = src[1];
            } else {
                a0 = make_uint4(0, 0, 0, 0); a1 = a0;
            }
            uint4* dst = (uint4*)&As[sr][sh * 16];
            dst[0] = a0; dst[1] = a1;
        }
        {   // stage B
            const uint4* src = (const uint4*)&wt[sr * DD + k0 + sh * 16];
            uint4* dst = (uint4*)&Bs[sr][sh * 16];
            dst[0] = src[0]; dst[1] = src[1];
        }
        __syncthreads();
        bf16x8 af[2], bf[8];
#pragma unroll
        for (int rf = 0; rf < 2; ++rf)
            af[rf] = *(const bf16x8*)&As[w * 32 + rf * 16 + hl][kg * 8];
#pragma unroll
        for (int cf = 0; cf < 8; ++cf)
            bf[cf] = *(const bf16x8*)&Bs[cf * 16 + hl][kg * 8];
#pragma unroll
        for (int rf = 0; rf < 2; ++rf)
#pragma unroll
            for (int cf = 0; cf < 8; ++cf)
                acc[rf][cf] = __builtin_amdgcn_mfma_f32_16x16x32_bf16(
                    af[rf], bf[cf], acc[rf][cf], 0, 0, 0);
        __syncthreads();
    }
#pragma unroll
    for (int rf = 0; rf < 2; ++rf) {
        int grow0 = row0 + w * 32 + rf * 16 + kg * 4;
#pragma unroll
        for (int j = 0; j < 4; ++j) {
            int grow = grow0 + j;
            if (grow < NN) {
                float s = 1.f / fmaxf((float)deg[grow], 1.f);
#pragma unroll
                for (int cf = 0; cf < 8; ++cf) {
                    int gcol = cf * 16 + hl;
                    float nv = bf2f((unsigned)newsb[(long long)grow * DD + gcol]);
                    xx[(long long)grow * DD + gcol] = nv + acc[rf][cf][j] * s;
                }
            }
        }
    }
}

// ---------------- user vector: mean of masked history embeddings ------------
__global__ __launch_bounds__(128) void user_vec_k(const int* __restrict__ hist,
                                                  const float* __restrict__ xx,
                                                  float* __restrict__ uv) {
    int b = blockIdx.x, t = threadIdx.x;
    float s = 0.f, cnt = 0.f;
    for (int h = 0; h < HL; ++h) {
        int id = hist[b * HL + h];
        if (id != 0) { s += xx[(long long)id * DD + t]; cnt += 1.f; }
    }
    uv[b * DD + t] = s / fmaxf(cnt, 1e-9f);
}

// ---------------- scores: dot(cand_emb, user_vec) ---------------------------
__global__ __launch_bounds__(64) void scores_k(const int* __restrict__ cand,
                                               const float* __restrict__ xx,
                                               const float* __restrict__ uv,
                                               float* __restrict__ out) {
    int b = blockIdx.x, t = threadIdx.x;
    float u0 = uv[b * DD + t];
    float u1 = uv[b * DD + 64 + t];
    for (int c = 0; c < CL; ++c) {
        int id = cand[b * CL + c];
        float p = u0 * xx[(long long)id * DD + t] +
                  u1 * xx[(long long)id * DD + 64 + t];
#pragma unroll
        for (int off = 32; off >= 1; off >>= 1) p += __shfl_xor(p, off);
        if (t == 0) out[b * CL + c] = p;
    }
}

extern "C" void kernel_launch(void* const* d_in, const int* in_sizes, int n_in,
                              void* d_out, int out_size, void* d_ws, size_t ws_size,
                              hipStream_t stream) {
    const float* x    = (const float*)d_in[0];
    // d_in[1] = n_id == arange(N) -> identity scatter, unused
    const int*   ei   = (const int*)d_in[2];
    const int*   hist = (const int*)d_in[3];
    const int*   cand = (const int*)d_in[4];
    const float* Wenc = (const float*)d_in[5];
    const float* Wgnn = (const float*)d_in[6];
    float* out = (float*)d_out;

    float*    xx      = (float*)d_ws;                    // [NN*DD] f32
    float*    uv      = xx + (size_t)NN * DD;            // [NB*DD] f32
    ushort_t* news_bf = (ushort_t*)(uv + (size_t)NB * DD); // [NN*DD] bf16
    ushort_t* agg_bf  = news_bf + (size_t)NN * DD;       // [NN*DD] bf16
    ushort_t* wt_enc  = agg_bf + (size_t)NN * DD;        // [128*320]
    ushort_t* wt_gnn  = wt_enc + 128 * KP;               // [128*128]
    int*      deg     = (int*)(wt_gnn + 128 * 128);      // [NN]
    int*      cur     = deg + NN;                        // [NN]
    int*      rs      = cur + NN;                        // [NN]
    int*      bsum    = rs + NN;                         // [NBLK]
    int*      boff    = bsum + NBLK;                     // [NBLK]
    int*      ssrc    = boff + NBLK;                     // [NE]

    hipMemsetAsync(deg, 0, 2 * (size_t)NN * sizeof(int), stream);

    prep_w<<<(128 * KP + 128 * 128 + 255) / 256, 256, 0, stream>>>(Wenc, Wgnn, wt_enc, wt_gnn);
    enc_mfma<<<(NN + 127) / 128, 256, 0, stream>>>(x, wt_enc, news_bf);

    k_hist<<<(NE + 255) / 256, 256, 0, stream>>>(ei, deg);
    k_scan1<<<NBLK, 256, 0, stream>>>(deg, rs, bsum);
    k_scan2<<<1, 512, 0, stream>>>(bsum, boff);
    k_scatter<<<(NE + 255) / 256, 256, 0, stream>>>(ei, rs, boff, cur, ssrc);
    k_aggregate<<<(NN + 3) / 4, 256, 0, stream>>>(ssrc, rs, boff, deg, news_bf, agg_bf);

    gnn_mfma<<<(NN + 127) / 128, 256, 0, stream>>>(agg_bf, wt_gnn, deg, news_bf, xx);
    user_vec_k<<<NB, 128, 0, stream>>>(hist, xx, uv);
    scores_k<<<NB, 64, 0, stream>>>(cand, xx, uv, out);
}

// Round 4
// 327.953 us; speedup vs baseline: 3.0818x; 1.2891x over previous
//
#include <hip/hip_runtime.h>

#define NN 100000      // nodes
#define DD 128         // embedding dim
#define KE 300         // raw feature dim
#define KP 320         // padded K for enc
#define NE 1600000     // edges
#define NB 4096        // batch (users)
#define HL 50          // history length
#define CL 20          // candidates
#define NBLK ((NN + 255) / 256)   // 391 scan blocks

typedef unsigned short ushort_t;
using bf16x8 = __attribute__((ext_vector_type(8))) short;
using f32x4  = __attribute__((ext_vector_type(4))) float;

__device__ __forceinline__ ushort_t f2bf(float f) {
    unsigned u = __float_as_uint(f);
    unsigned r = u + 0x7FFF + ((u >> 16) & 1);   // RNE
    return (ushort_t)(r >> 16);
}
__device__ __forceinline__ float bf2f(unsigned s) {
    return __uint_as_float(s << 16);
}

// ---------------- weight prep: transpose + convert to bf16 ------------------
__global__ __launch_bounds__(256) void prep_w(const float* __restrict__ We,
                                              const float* __restrict__ Wg,
                                              ushort_t* __restrict__ wte,
                                              ushort_t* __restrict__ wtg) {
    int i = blockIdx.x * 256 + threadIdx.x;
    if (i < 128 * KP) {
        int n = i / KP, k = i - n * KP;
        float v = (k < KE) ? We[k * DD + n] : 0.f;
        wte[n * KP + k] = f2bf(v);
    } else if (i < 128 * KP + 128 * 128) {
        int j = i - 128 * KP;
        int n = j >> 7, k = j & 127;
        wtg[n * DD + k] = f2bf(Wg[k * DD + n]);
    }
}

// ---------------- encoder: news_bf[M,128] = bf16( x[M,300] @ W[300,128] ) ---
__global__ __launch_bounds__(256) void enc_mfma(const float* __restrict__ x,
                                                const ushort_t* __restrict__ wt,
                                                ushort_t* __restrict__ news) {
    __shared__ ushort_t As[128][40];   // [row][k] bf16
    __shared__ ushort_t Bs[128][40];   // [col][k] bf16 (B^T)
    const int tid = threadIdx.x;
    const int w = tid >> 6, lane = tid & 63;
    const int hl = lane & 15, kg = lane >> 4;
    const int row0 = blockIdx.x * 128;
    const int sr = tid >> 1, sh = tid & 1;      // staging: row, half

    f32x4 acc[2][8];
#pragma unroll
    for (int i = 0; i < 2; ++i)
#pragma unroll
        for (int j = 0; j < 8; ++j) acc[i][j] = (f32x4)0.f;

    for (int k0 = 0; k0 < KP; k0 += 32) {
        // ---- stage A: 128 rows x 32 k, fp32 -> bf16, 16 floats/thread
        {
            int row = row0 + sr;
            int kb = k0 + sh * 16;
            float v[16];
            if (row < NN && kb + 16 <= KE) {
                const float4* px = (const float4*)&x[(long long)row * KE + kb];
                float4 a0 = px[0], a1 = px[1], a2 = px[2], a3 = px[3];
                v[0]=a0.x; v[1]=a0.y; v[2]=a0.z; v[3]=a0.w;
                v[4]=a1.x; v[5]=a1.y; v[6]=a1.z; v[7]=a1.w;
                v[8]=a2.x; v[9]=a2.y; v[10]=a2.z; v[11]=a2.w;
                v[12]=a3.x; v[13]=a3.y; v[14]=a3.z; v[15]=a3.w;
            } else {
#pragma unroll
                for (int j = 0; j < 16; ++j) {
                    int k = kb + j;
                    v[j] = (row < NN && k < KE) ? x[(long long)row * KE + k] : 0.f;
                }
            }
            unsigned p[8];
#pragma unroll
            for (int j = 0; j < 8; ++j)
                p[j] = (unsigned)f2bf(v[2*j]) | ((unsigned)f2bf(v[2*j+1]) << 16);
            uint4* dst = (uint4*)&As[sr][sh * 16];
            dst[0] = make_uint4(p[0], p[1], p[2], p[3]);
            dst[1] = make_uint4(p[4], p[5], p[6], p[7]);
        }
        // ---- stage B
        {
            const uint4* src = (const uint4*)&wt[sr * KP + k0 + sh * 16];
            uint4* dst = (uint4*)&Bs[sr][sh * 16];
            dst[0] = src[0];
            dst[1] = src[1];
        }
        __syncthreads();
        bf16x8 af[2], bfr[8];
#pragma unroll
        for (int rf = 0; rf < 2; ++rf)
            af[rf] = *(const bf16x8*)&As[w * 32 + rf * 16 + hl][kg * 8];
#pragma unroll
        for (int cf = 0; cf < 8; ++cf)
            bfr[cf] = *(const bf16x8*)&Bs[cf * 16 + hl][kg * 8];
#pragma unroll
        for (int rf = 0; rf < 2; ++rf)
#pragma unroll
            for (int cf = 0; cf < 8; ++cf)
                acc[rf][cf] = __builtin_amdgcn_mfma_f32_16x16x32_bf16(
                    af[rf], bfr[cf], acc[rf][cf], 0, 0, 0);
        __syncthreads();
    }
#pragma unroll
    for (int rf = 0; rf < 2; ++rf)
#pragma unroll
        for (int cf = 0; cf < 8; ++cf)
#pragma unroll
            for (int j = 0; j < 4; ++j) {
                int grow = row0 + w * 32 + rf * 16 + kg * 4 + j;
                int gcol = cf * 16 + hl;
                if (grow < NN)
                    news[(long long)grow * DD + gcol] = f2bf(acc[rf][cf][j]);
            }
}

// ---------------- CSR build step 1: degree histogram ------------------------
__global__ __launch_bounds__(256) void k_hist(const int* __restrict__ ei,
                                              int* __restrict__ deg) {
    int e = blockIdx.x * 256 + threadIdx.x;
    if (e < NE) atomicAdd(&deg[ei[NE + e]], 1);
}

// ---------------- CSR step 2a: per-block exclusive scan of deg --------------
__global__ __launch_bounds__(256) void k_scan1(const int* __restrict__ deg,
                                               int* __restrict__ rs,
                                               int* __restrict__ bsum) {
    __shared__ int s[256];
    int t = threadIdx.x, idx = blockIdx.x * 256 + t;
    int v = (idx < NN) ? deg[idx] : 0;
    s[t] = v;
    __syncthreads();
#pragma unroll
    for (int off = 1; off < 256; off <<= 1) {
        int add = (t >= off) ? s[t - off] : 0;
        __syncthreads();
        s[t] += add;
        __syncthreads();
    }
    if (idx < NN) rs[idx] = s[t] - v;
    if (t == 255) bsum[blockIdx.x] = s[255];
}

// ---------------- CSR step 2b: scan block sums ------------------------------
__global__ __launch_bounds__(512) void k_scan2(const int* __restrict__ bsum,
                                               int* __restrict__ boff) {
    __shared__ int s[512];
    int t = threadIdx.x;
    int v = (t < NBLK) ? bsum[t] : 0;
    s[t] = v;
    __syncthreads();
#pragma unroll
    for (int off = 1; off < 512; off <<= 1) {
        int add = (t >= off) ? s[t - off] : 0;
        __syncthreads();
        s[t] += add;
        __syncthreads();
    }
    if (t < NBLK) boff[t] = s[t] - v;
}

// ---------------- CSR step 3: scatter src ids into dst-grouped order --------
__global__ __launch_bounds__(256) void k_scatter(const int* __restrict__ ei,
                                                 const int* __restrict__ rs,
                                                 const int* __restrict__ boff,
                                                 int* __restrict__ cursor,
                                                 int* __restrict__ ssrc) {
    int e = blockIdx.x * 256 + threadIdx.x;
    if (e >= NE) return;
    int src = ei[e];
    int dst = ei[NE + e];
    int pos = rs[dst] + boff[dst >> 8] + atomicAdd(&cursor[dst], 1);
    ssrc[pos] = src;
}

// ---------------- aggregation: wave per node, 4 edges in flight, 16B loads --
// lane = (e, l): e = lane>>4 edge slot, l = lane&15 16B chunk of the 256B row.
__global__ __launch_bounds__(256) void k_aggregate(const int* __restrict__ ssrc,
                                                   const int* __restrict__ rs,
                                                   const int* __restrict__ boff,
                                                   const int* __restrict__ deg,
                                                   const ushort_t* __restrict__ news,
                                                   ushort_t* __restrict__ agg) {
    int n = blockIdx.x * 4 + (threadIdx.x >> 6);
    if (n >= NN) return;
    int lane = threadIdx.x & 63;
    int e = lane >> 4;        // edge slot 0..3
    int l = lane & 15;        // chunk 0..15 (8 bf16 = 16B)
    int start = rs[n] + boff[n >> 8];
    int cnt = deg[n];

    float acc[8];
#pragma unroll
    for (int j = 0; j < 8; ++j) acc[j] = 0.f;

    for (int i = 0; i < cnt; i += 4) {
        int ii = i + e;
        uint4 v = make_uint4(0u, 0u, 0u, 0u);
        if (ii < cnt) {
            int src = ssrc[start + ii];
            v = *(const uint4*)&news[(long long)src * DD + l * 8];
        }
        acc[0] += bf2f(v.x & 0xFFFFu); acc[1] += bf2f(v.x >> 16);
        acc[2] += bf2f(v.y & 0xFFFFu); acc[3] += bf2f(v.y >> 16);
        acc[4] += bf2f(v.z & 0xFFFFu); acc[5] += bf2f(v.z >> 16);
        acc[6] += bf2f(v.w & 0xFFFFu); acc[7] += bf2f(v.w >> 16);
    }
    // reduce across the 4 edge slots (lane bits 4 and 5)
#pragma unroll
    for (int j = 0; j < 8; ++j) {
        acc[j] += __shfl_xor(acc[j], 16);
        acc[j] += __shfl_xor(acc[j], 32);
    }
    if (e == 0) {
        uint4 o;
        o.x = (unsigned)f2bf(acc[0]) | ((unsigned)f2bf(acc[1]) << 16);
        o.y = (unsigned)f2bf(acc[2]) | ((unsigned)f2bf(acc[3]) << 16);
        o.z = (unsigned)f2bf(acc[4]) | ((unsigned)f2bf(acc[5]) << 16);
        o.w = (unsigned)f2bf(acc[6]) | ((unsigned)f2bf(acc[7]) << 16);
        *(uint4*)&agg[(long long)n * DD + l * 8] = o;
    }
}

// ---------------- gnn: xx = f32(news) + (agg @ Wgnn) / deg  (MFMA bf16) -----
__global__ __launch_bounds__(256) void gnn_mfma(const ushort_t* __restrict__ aggb,
                                                const ushort_t* __restrict__ wt,
                                                const int* __restrict__ deg,
                                                const ushort_t* __restrict__ newsb,
                                                float* __restrict__ xx) {
    __shared__ ushort_t As[128][40];
    __shared__ ushort_t Bs[128][40];
    const int tid = threadIdx.x;
    const int w = tid >> 6, lane = tid & 63;
    const int hl = lane & 15, kg = lane >> 4;
    const int row0 = blockIdx.x * 128;
    const int sr = tid >> 1, sh = tid & 1;

    f32x4 acc[2][8];
#pragma unroll
    for (int i = 0; i < 2; ++i)
#pragma unroll
        for (int j = 0; j < 8; ++j) acc[i][j] = (f32x4)0.f;

    for (int k0 = 0; k0 < DD; k0 += 32) {
        {   // stage A (bf16 agg rows)
            int row = row0 + sr;
            uint4 a0, a1;
            if (row < NN) {
                const uint4* src = (const uint4*)&aggb[(long long)row * DD + k0 + sh * 16];
                a0 = src[0]; a1 = src[1];
            } else {
                a0 = make_uint4(0, 0, 0, 0); a1 = a0;
            }
            uint4* dst = (uint4*)&As[sr][sh * 16];
            dst[0] = a0; dst[1] = a1;
        }
        {   // stage B
            const uint4* src = (const uint4*)&wt[sr * DD + k0 + sh * 16];
            uint4* dst = (uint4*)&Bs[sr][sh * 16];
            dst[0] = src[0]; dst[1] = src[1];
        }
        __syncthreads();
        bf16x8 af[2], bfr[8];
#pragma unroll
        for (int rf = 0; rf < 2; ++rf)
            af[rf] = *(const bf16x8*)&As[w * 32 + rf * 16 + hl][kg * 8];
#pragma unroll
        for (int cf = 0; cf < 8; ++cf)
            bfr[cf] = *(const bf16x8*)&Bs[cf * 16 + hl][kg * 8];
#pragma unroll
        for (int rf = 0; rf < 2; ++rf)
#pragma unroll
            for (int cf = 0; cf < 8; ++cf)
                acc[rf][cf] = __builtin_amdgcn_mfma_f32_16x16x32_bf16(
                    af[rf], bfr[cf], acc[rf][cf], 0, 0, 0);
        __syncthreads();
    }
#pragma unroll
    for (int rf = 0; rf < 2; ++rf) {
        int grow0 = row0 + w * 32 + rf * 16 + kg * 4;
#pragma unroll
        for (int j = 0; j < 4; ++j) {
            int grow = grow0 + j;
            if (grow < NN) {
                float s = 1.f / fmaxf((float)deg[grow], 1.f);
#pragma unroll
                for (int cf = 0; cf < 8; ++cf) {
                    int gcol = cf * 16 + hl;
                    float nv = bf2f((unsigned)newsb[(long long)grow * DD + gcol]);
                    xx[(long long)grow * DD + gcol] = nv + acc[rf][cf][j] * s;
                }
            }
        }
    }
}

// ---------------- user vector: mean of masked history embeddings ------------
__global__ __launch_bounds__(128) void user_vec_k(const int* __restrict__ hist,
                                                  const float* __restrict__ xx,
                                                  float* __restrict__ uv) {
    int b = blockIdx.x, t = threadIdx.x;
    float s = 0.f, cnt = 0.f;
    for (int h = 0; h < HL; ++h) {
        int id = hist[b * HL + h];
        if (id != 0) { s += xx[(long long)id * DD + t]; cnt += 1.f; }
    }
    uv[b * DD + t] = s / fmaxf(cnt, 1e-9f);
}

// ---------------- scores: dot(cand_emb, user_vec) ---------------------------
__global__ __launch_bounds__(64) void scores_k(const int* __restrict__ cand,
                                               const float* __restrict__ xx,
                                               const float* __restrict__ uv,
                                               float* __restrict__ out) {
    int b = blockIdx.x, t = threadIdx.x;
    float u0 = uv[b * DD + t];
    float u1 = uv[b * DD + 64 + t];
    for (int c = 0; c < CL; ++c) {
        int id = cand[b * CL + c];
        float p = u0 * xx[(long long)id * DD + t] +
                  u1 * xx[(long long)id * DD + 64 + t];
#pragma unroll
        for (int off = 32; off >= 1; off >>= 1) p += __shfl_xor(p, off);
        if (t == 0) out[b * CL + c] = p;
    }
}

extern "C" void kernel_launch(void* const* d_in, const int* in_sizes, int n_in,
                              void* d_out, int out_size, void* d_ws, size_t ws_size,
                              hipStream_t stream) {
    const float* x    = (const float*)d_in[0];
    // d_in[1] = n_id == arange(N) -> identity scatter, unused
    const int*   ei   = (const int*)d_in[2];
    const int*   hist = (const int*)d_in[3];
    const int*   cand = (const int*)d_in[4];
    const float* Wenc = (const float*)d_in[5];
    const float* Wgnn = (const float*)d_in[6];
    float* out = (float*)d_out;

    float*    xx      = (float*)d_ws;                    // [NN*DD] f32
    float*    uv      = xx + (size_t)NN * DD;            // [NB*DD] f32
    ushort_t* news_bf = (ushort_t*)(uv + (size_t)NB * DD); // [NN*DD] bf16
    ushort_t* agg_bf  = news_bf + (size_t)NN * DD;       // [NN*DD] bf16
    ushort_t* wt_enc  = agg_bf + (size_t)NN * DD;        // [128*320]
    ushort_t* wt_gnn  = wt_enc + 128 * KP;               // [128*128]
    int*      deg     = (int*)(wt_gnn + 128 * 128);      // [NN]
    int*      cur     = deg + NN;                        // [NN]
    int*      rs      = cur + NN;                        // [NN]
    int*      bsum    = rs + NN;                         // [NBLK]
    int*      boff    = bsum + NBLK;                     // [NBLK]
    int*      ssrc    = boff + NBLK;                     // [NE]

    hipMemsetAsync(deg, 0, 2 * (size_t)NN * sizeof(int), stream);

    prep_w<<<(128 * KP + 128 * 128 + 255) / 256, 256, 0, stream>>>(Wenc, Wgnn, wt_enc, wt_gnn);
    enc_mfma<<<(NN + 127) / 128, 256, 0, stream>>>(x, wt_enc, news_bf);

    k_hist<<<(NE + 255) / 256, 256, 0, stream>>>(ei, deg);
    k_scan1<<<NBLK, 256, 0, stream>>>(deg, rs, bsum);
    k_scan2<<<1, 512, 0, stream>>>(bsum, boff);
    k_scatter<<<(NE + 255) / 256, 256, 0, stream>>>(ei, rs, boff, cur, ssrc);
    k_aggregate<<<(NN + 3) / 4, 256, 0, stream>>>(ssrc, rs, boff, deg, news_bf, agg_bf);

    gnn_mfma<<<(NN + 127) / 128, 256, 0, stream>>>(agg_bf, wt_gnn, deg, news_bf, xx);
    user_vec_k<<<NB, 128, 0, stream>>>(hist, xx, uv);
    scores_k<<<NB, 64, 0, stream>>>(cand, xx, uv, out);
}

// Round 5
// 198.788 us; speedup vs baseline: 5.0843x; 1.6498x over previous
//
#include <hip/hip_runtime.h>

#define NN 100000      // nodes
#define DD 128         // embedding dim
#define KE 300         // raw feature dim
#define KP 320         // padded K for enc
#define NE 1600000     // edges
#define NB 4096        // batch (users)
#define HL 50          // history length
#define CL 20          // candidates

#define NBUCK 391      // ceil(NN/256): buckets of 256 dst nodes
#define SLOT  4736     // max edges/bucket (avg 4096, +10 sigma margin)
#define PBLK  250      // partition blocks
#define EPB   6400     // edges per partition block = NE/PBLK
#define EPT   25       // edges per thread = EPB/256

typedef unsigned short ushort_t;
using bf16x8 = __attribute__((ext_vector_type(8))) short;
using f32x4  = __attribute__((ext_vector_type(4))) float;

__device__ __forceinline__ ushort_t f2bf(float f) {
    unsigned u = __float_as_uint(f);
    unsigned r = u + 0x7FFF + ((u >> 16) & 1);   // RNE
    return (ushort_t)(r >> 16);
}
__device__ __forceinline__ float bf2f(unsigned s) {
    return __uint_as_float(s << 16);
}

// ---------------- weight prep: transpose + convert to bf16 ------------------
__global__ __launch_bounds__(256) void prep_w(const float* __restrict__ We,
                                              const float* __restrict__ Wg,
                                              ushort_t* __restrict__ wte,
                                              ushort_t* __restrict__ wtg) {
    int i = blockIdx.x * 256 + threadIdx.x;
    if (i < 128 * KP) {
        int n = i / KP, k = i - n * KP;
        float v = (k < KE) ? We[k * DD + n] : 0.f;
        wte[n * KP + k] = f2bf(v);
    } else if (i < 128 * KP + 128 * 128) {
        int j = i - 128 * KP;
        int n = j >> 7, k = j & 127;
        wtg[n * DD + k] = f2bf(Wg[k * DD + n]);
    }
}

// ---------------- encoder: news_bf[M,128] = bf16( x[M,300] @ W[300,128] ) ---
__global__ __launch_bounds__(256) void enc_mfma(const float* __restrict__ x,
                                                const ushort_t* __restrict__ wt,
                                                ushort_t* __restrict__ news) {
    __shared__ ushort_t As[128][40];   // [row][k] bf16
    __shared__ ushort_t Bs[128][40];   // [col][k] bf16 (B^T)
    const int tid = threadIdx.x;
    const int w = tid >> 6, lane = tid & 63;
    const int hl = lane & 15, kg = lane >> 4;
    const int row0 = blockIdx.x * 128;
    const int sr = tid >> 1, sh = tid & 1;      // staging: row, half

    f32x4 acc[2][8];
#pragma unroll
    for (int i = 0; i < 2; ++i)
#pragma unroll
        for (int j = 0; j < 8; ++j) acc[i][j] = (f32x4)0.f;

    for (int k0 = 0; k0 < KP; k0 += 32) {
        // ---- stage A: 128 rows x 32 k, fp32 -> bf16, 16 floats/thread
        {
            int row = row0 + sr;
            int kb = k0 + sh * 16;
            float v[16];
            if (row < NN && kb + 16 <= KE) {
                const float4* px = (const float4*)&x[(long long)row * KE + kb];
                float4 a0 = px[0], a1 = px[1], a2 = px[2], a3 = px[3];
                v[0]=a0.x; v[1]=a0.y; v[2]=a0.z; v[3]=a0.w;
                v[4]=a1.x; v[5]=a1.y; v[6]=a1.z; v[7]=a1.w;
                v[8]=a2.x; v[9]=a2.y; v[10]=a2.z; v[11]=a2.w;
                v[12]=a3.x; v[13]=a3.y; v[14]=a3.z; v[15]=a3.w;
            } else {
#pragma unroll
                for (int j = 0; j < 16; ++j) {
                    int k = kb + j;
                    v[j] = (row < NN && k < KE) ? x[(long long)row * KE + k] : 0.f;
                }
            }
            unsigned p[8];
#pragma unroll
            for (int j = 0; j < 8; ++j)
                p[j] = (unsigned)f2bf(v[2*j]) | ((unsigned)f2bf(v[2*j+1]) << 16);
            uint4* dst = (uint4*)&As[sr][sh * 16];
            dst[0] = make_uint4(p[0], p[1], p[2], p[3]);
            dst[1] = make_uint4(p[4], p[5], p[6], p[7]);
        }
        // ---- stage B
        {
            const uint4* src = (const uint4*)&wt[sr * KP + k0 + sh * 16];
            uint4* dst = (uint4*)&Bs[sr][sh * 16];
            dst[0] = src[0];
            dst[1] = src[1];
        }
        __syncthreads();
        bf16x8 af[2], bfr[8];
#pragma unroll
        for (int rf = 0; rf < 2; ++rf)
            af[rf] = *(const bf16x8*)&As[w * 32 + rf * 16 + hl][kg * 8];
#pragma unroll
        for (int cf = 0; cf < 8; ++cf)
            bfr[cf] = *(const bf16x8*)&Bs[cf * 16 + hl][kg * 8];
#pragma unroll
        for (int rf = 0; rf < 2; ++rf)
#pragma unroll
            for (int cf = 0; cf < 8; ++cf)
                acc[rf][cf] = __builtin_amdgcn_mfma_f32_16x16x32_bf16(
                    af[rf], bfr[cf], acc[rf][cf], 0, 0, 0);
        __syncthreads();
    }
#pragma unroll
    for (int rf = 0; rf < 2; ++rf)
#pragma unroll
        for (int cf = 0; cf < 8; ++cf)
#pragma unroll
            for (int j = 0; j < 4; ++j) {
                int grow = row0 + w * 32 + rf * 16 + kg * 4 + j;
                int gcol = cf * 16 + hl;
                if (grow < NN)
                    news[(long long)grow * DD + gcol] = f2bf(acc[rf][cf][j]);
            }
}

// ---------------- partition: edges -> 391 buckets of 256 dsts ---------------
// Packed entry: (src << 8) | (dst & 255).  Block reserves per-bucket runs so
// writes form ~64B contiguous chunks owned by one block (XCD-local lines).
__global__ __launch_bounds__(256) void k_part(const int* __restrict__ ei,
                                              unsigned* __restrict__ gcur,
                                              unsigned* __restrict__ pairs) {
    __shared__ unsigned hist[NBUCK], rbase[NBUCK], lcur[NBUCK];
    const int tid = threadIdx.x;
    const int eb = blockIdx.x * EPB;

    for (int i = tid; i < NBUCK; i += 256) hist[i] = 0;
    __syncthreads();

    unsigned val[EPT], bk[EPT];
#pragma unroll
    for (int l = 0; l < EPT; ++l) {
        int e = eb + l * 256 + tid;
        unsigned src = (unsigned)ei[e];
        unsigned dst = (unsigned)ei[NE + e];
        val[l] = (src << 8) | (dst & 255u);
        bk[l] = dst >> 8;
        atomicAdd(&hist[bk[l]], 1u);
    }
    __syncthreads();

    for (int i = tid; i < NBUCK; i += 256) {
        unsigned h = hist[i];
        rbase[i] = (unsigned)i * SLOT + (h ? atomicAdd(&gcur[i], h) : 0u);
        lcur[i] = 0;
    }
    __syncthreads();

#pragma unroll
    for (int l = 0; l < EPT; ++l) {
        unsigned b = bk[l];
        unsigned pos = rbase[b] + atomicAdd(&lcur[b], 1u);
        if (pos < (b + 1u) * SLOT) pairs[pos] = val[l];   // overflow guard
    }
}

// ---------------- bucket aggregate: local CSR in LDS + register gather ------
__global__ __launch_bounds__(512) void k_bagg(const unsigned* __restrict__ gcur,
                                              const unsigned* __restrict__ pairs,
                                              const ushort_t* __restrict__ news,
                                              ushort_t* __restrict__ agg,
                                              int* __restrict__ deg) {
    __shared__ unsigned srcs[SLOT];
    __shared__ unsigned hist[256], base[256], cur[256], sb[256];
    const int tid = threadIdx.x;
    const int b = blockIdx.x;
    int cnt = (int)gcur[b];
    if (cnt > SLOT) cnt = SLOT;

    if (tid < 256) hist[tid] = 0;
    __syncthreads();
    for (int i = tid; i < cnt; i += 512)
        atomicAdd(&hist[pairs[b * SLOT + i] & 255u], 1u);
    __syncthreads();

    // exclusive scan hist -> base (Hillis-Steele over 256 entries)
    if (tid < 256) sb[tid] = hist[tid];
    __syncthreads();
    for (int off = 1; off < 256; off <<= 1) {
        unsigned add = 0;
        if (tid < 256 && tid >= off) add = sb[tid - off];
        __syncthreads();
        if (tid < 256) sb[tid] += add;
        __syncthreads();
    }
    if (tid < 256) { unsigned bb = sb[tid] - hist[tid]; base[tid] = bb; cur[tid] = bb; }
    __syncthreads();

    // LDS scatter: group srcs by local dst
    for (int i = tid; i < cnt; i += 512) {
        unsigned v = pairs[b * SLOT + i];
        unsigned pos = atomicAdd(&cur[v & 255u], 1u);
        srcs[pos] = v >> 8;
    }
    __syncthreads();

    // wave per dst: 4 edges in flight, 16B/lane gathers, register accum
    const int w = tid >> 6, lane = tid & 63;
    const int e = lane >> 4, l = lane & 15;
    for (int d = w; d < 256; d += 8) {
        int gd = b * 256 + d;
        if (gd >= NN) break;                 // d uniform per wave
        int s0 = (int)base[d], c = (int)hist[d];
        float acc[8];
#pragma unroll
        for (int j = 0; j < 8; ++j) acc[j] = 0.f;
        for (int i = 0; i < c; i += 4) {
            int ii = i + e;
            uint4 v = make_uint4(0u, 0u, 0u, 0u);
            if (ii < c) {
                unsigned src = srcs[s0 + ii];
                v = *(const uint4*)&news[(long long)src * DD + l * 8];
            }
            acc[0] += bf2f(v.x & 0xFFFFu); acc[1] += bf2f(v.x >> 16);
            acc[2] += bf2f(v.y & 0xFFFFu); acc[3] += bf2f(v.y >> 16);
            acc[4] += bf2f(v.z & 0xFFFFu); acc[5] += bf2f(v.z >> 16);
            acc[6] += bf2f(v.w & 0xFFFFu); acc[7] += bf2f(v.w >> 16);
        }
#pragma unroll
        for (int j = 0; j < 8; ++j) {
            acc[j] += __shfl_xor(acc[j], 16);
            acc[j] += __shfl_xor(acc[j], 32);
        }
        if (e == 0) {
            uint4 o;
            o.x = (unsigned)f2bf(acc[0]) | ((unsigned)f2bf(acc[1]) << 16);
            o.y = (unsigned)f2bf(acc[2]) | ((unsigned)f2bf(acc[3]) << 16);
            o.z = (unsigned)f2bf(acc[4]) | ((unsigned)f2bf(acc[5]) << 16);
            o.w = (unsigned)f2bf(acc[6]) | ((unsigned)f2bf(acc[7]) << 16);
            *(uint4*)&agg[(long long)gd * DD + l * 8] = o;
            if (l == 0) deg[gd] = c;
        }
    }
}

// ---------------- gnn: xx = f32(news) + (agg @ Wgnn) / deg  (MFMA bf16) -----
__global__ __launch_bounds__(256) void gnn_mfma(const ushort_t* __restrict__ aggb,
                                                const ushort_t* __restrict__ wt,
                                                const int* __restrict__ deg,
                                                const ushort_t* __restrict__ newsb,
                                                float* __restrict__ xx) {
    __shared__ ushort_t As[128][40];
    __shared__ ushort_t Bs[128][40];
    const int tid = threadIdx.x;
    const int w = tid >> 6, lane = tid & 63;
    const int hl = lane & 15, kg = lane >> 4;
    const int row0 = blockIdx.x * 128;
    const int sr = tid >> 1, sh = tid & 1;

    f32x4 acc[2][8];
#pragma unroll
    for (int i = 0; i < 2; ++i)
#pragma unroll
        for (int j = 0; j < 8; ++j) acc[i][j] = (f32x4)0.f;

    for (int k0 = 0; k0 < DD; k0 += 32) {
        {   // stage A (bf16 agg rows)
            int row = row0 + sr;
            uint4 a0, a1;
            if (row < NN) {
                const uint4* src = (const uint4*)&aggb[(long long)row * DD + k0 + sh * 16];
                a0 = src[0]; a1 = src[1];
            } else {
                a0 = make_uint4(0, 0, 0, 0); a1 = a0;
            }
            uint4* dst = (uint4*)&As[sr][sh * 16];
            dst[0] = a0; dst[1] = a1;
        }
        {   // stage B
            const uint4* src = (const uint4*)&wt[sr * DD + k0 + sh * 16];
            uint4* dst = (uint4*)&Bs[sr][sh * 16];
            dst[0] = src[0]; dst[1] = src[1];
        }
        __syncthreads();
        bf16x8 af[2], bfr[8];
#pragma unroll
        for (int rf = 0; rf < 2; ++rf)
            af[rf] = *(const bf16x8*)&As[w * 32 + rf * 16 + hl][kg * 8];
#pragma unroll
        for (int cf = 0; cf < 8; ++cf)
            bfr[cf] = *(const bf16x8*)&Bs[cf * 16 + hl][kg * 8];
#pragma unroll
        for (int rf = 0; rf < 2; ++rf)
#pragma unroll
            for (int cf = 0; cf < 8; ++cf)
                acc[rf][cf] = __builtin_amdgcn_mfma_f32_16x16x32_bf16(
                    af[rf], bfr[cf], acc[rf][cf], 0, 0, 0);
        __syncthreads();
    }
#pragma unroll
    for (int rf = 0; rf < 2; ++rf) {
        int grow0 = row0 + w * 32 + rf * 16 + kg * 4;
#pragma unroll
        for (int j = 0; j < 4; ++j) {
            int grow = grow0 + j;
            if (grow < NN) {
                float s = 1.f / fmaxf((float)deg[grow], 1.f);
#pragma unroll
                for (int cf = 0; cf < 8; ++cf) {
                    int gcol = cf * 16 + hl;
                    float nv = bf2f((unsigned)newsb[(long long)grow * DD + gcol]);
                    xx[(long long)grow * DD + gcol] = nv + acc[rf][cf][j] * s;
                }
            }
        }
    }
}

// ---------------- user vector: mean of masked history embeddings ------------
__global__ __launch_bounds__(128) void user_vec_k(const int* __restrict__ hist,
                                                  const float* __restrict__ xx,
                                                  float* __restrict__ uv) {
    int b = blockIdx.x, t = threadIdx.x;
    float s = 0.f, cnt = 0.f;
    for (int h = 0; h < HL; ++h) {
        int id = hist[b * HL + h];
        if (id != 0) { s += xx[(long long)id * DD + t]; cnt += 1.f; }
    }
    uv[b * DD + t] = s / fmaxf(cnt, 1e-9f);
}

// ---------------- scores: dot(cand_emb, user_vec) ---------------------------
__global__ __launch_bounds__(64) void scores_k(const int* __restrict__ cand,
                                               const float* __restrict__ xx,
                                               const float* __restrict__ uv,
                                               float* __restrict__ out) {
    int b = blockIdx.x, t = threadIdx.x;
    float u0 = uv[b * DD + t];
    float u1 = uv[b * DD + 64 + t];
    for (int c = 0; c < CL; ++c) {
        int id = cand[b * CL + c];
        float p = u0 * xx[(long long)id * DD + t] +
                  u1 * xx[(long long)id * DD + 64 + t];
#pragma unroll
        for (int off = 32; off >= 1; off >>= 1) p += __shfl_xor(p, off);
        if (t == 0) out[b * CL + c] = p;
    }
}

extern "C" void kernel_launch(void* const* d_in, const int* in_sizes, int n_in,
                              void* d_out, int out_size, void* d_ws, size_t ws_size,
                              hipStream_t stream) {
    const float* x    = (const float*)d_in[0];
    // d_in[1] = n_id == arange(N) -> identity scatter, unused
    const int*   ei   = (const int*)d_in[2];
    const int*   hist = (const int*)d_in[3];
    const int*   cand = (const int*)d_in[4];
    const float* Wenc = (const float*)d_in[5];
    const float* Wgnn = (const float*)d_in[6];
    float* out = (float*)d_out;

    float*    xx      = (float*)d_ws;                      // [NN*DD] f32
    float*    uv      = xx + (size_t)NN * DD;              // [NB*DD] f32
    ushort_t* news_bf = (ushort_t*)(uv + (size_t)NB * DD); // [NN*DD] bf16
    ushort_t* agg_bf  = news_bf + (size_t)NN * DD;         // [NN*DD] bf16
    ushort_t* wt_enc  = agg_bf + (size_t)NN * DD;          // [128*KP]
    ushort_t* wt_gnn  = wt_enc + 128 * KP;                 // [128*128]
    int*      deg     = (int*)(wt_gnn + 128 * 128);        // [NN]
    unsigned* gcur    = (unsigned*)(deg + NN);             // [NBUCK]
    unsigned* pairs   = gcur + NBUCK;                      // [NBUCK*SLOT]

    hipMemsetAsync(gcur, 0, NBUCK * sizeof(unsigned), stream);

    prep_w<<<(128 * KP + 128 * 128 + 255) / 256, 256, 0, stream>>>(Wenc, Wgnn, wt_enc, wt_gnn);
    enc_mfma<<<(NN + 127) / 128, 256, 0, stream>>>(x, wt_enc, news_bf);

    k_part<<<PBLK, 256, 0, stream>>>(ei, gcur, pairs);
    k_bagg<<<NBUCK, 512, 0, stream>>>(gcur, pairs, news_bf, agg_bf, deg);

    gnn_mfma<<<(NN + 127) / 128, 256, 0, stream>>>(agg_bf, wt_gnn, deg, news_bf, xx);
    user_vec_k<<<NB, 128, 0, stream>>>(hist, xx, uv);
    scores_k<<<NB, 64, 0, stream>>>(cand, xx, uv, out);
}